// Round 6
// baseline (272.152 us; speedup 1.0000x reference)
//
#include <hip/hip_runtime.h>

#define BROWS 131072
#define MDIM 64
#define NDIM 121
#define STAGES 9
#define RPB 64   // rows per block in gemm

// ws layout (floats):
//   [0,     4096)  R    (64x64)
//   [4096, 11840)  PhiT (121x64)
//   [12288, 20032) GT   (121x64)   GT[n][k] = (F_9 * Phi)[k][n]

// ---------------------------------------------------------------- kernel A
__global__ void prep_kernel(const float* __restrict__ Phi,
                            float* __restrict__ R,
                            float* __restrict__ PhiT) {
    int id = blockIdx.x * blockDim.x + threadIdx.x;
    if (id < MDIM * MDIM) {
        int i = id >> 6, j = id & 63;
        const float* a = Phi + i * NDIM;
        const float* b = Phi + j * NDIM;
        float s0 = 0.f, s1 = 0.f, s2 = 0.f, s3 = 0.f;
        for (int n = 0; n < 120; n += 4) {
            s0 += a[n + 0] * b[n + 0];
            s1 += a[n + 1] * b[n + 1];
            s2 += a[n + 2] * b[n + 2];
            s3 += a[n + 3] * b[n + 3];
        }
        R[id] = (s0 + s1) + (s2 + s3) + a[120] * b[120];
    }
    int id2 = id - MDIM * MDIM;
    if (id2 >= 0 && id2 < NDIM * MDIM) {
        int n = id2 >> 6, k = id2 & 63;
        PhiT[id2] = Phi[k * NDIM + n];
    }
}

// ---------------------------------------------------------------- kernel B
// F-recurrence: 1 block, 4 waves, lane = row i, F row in VGPRs (static idx
// only). R rows are read via the SCALAR path: readfirstlane(j) makes the
// address provably uniform -> s_load (R is 16 KB, scalar-cache resident),
// keeping the LDS pipe free. LDS holds only the F-column exchange
// (sFT[j*65+i], stride 65 -> conflict-free).
__global__ __launch_bounds__(256) void fmat_kernel(const float* __restrict__ R,
                                                   const float* __restrict__ PhiT,
                                                   const float* __restrict__ gammas,
                                                   float* __restrict__ GT) {
    __shared__ float sFT[MDIM * 65];   // sFT[j*65+i] = F[i][j]
    const int tid = threadIdx.x;
    const int lane = tid & 63;
    const int wave = tid >> 6;         // 0..3

    for (int q = tid; q < 4096; q += 256) {
        int j = q >> 6, i = q & 63;
        sFT[j * 65 + i] = (i == j) ? 1.f : 0.f;
    }
    float f[64];
#pragma unroll
    for (int m = 0; m < 64; ++m) f[m] = (lane == m) ? 1.f : 0.f;
    __syncthreads();

    for (int s = 0; s < STAGES; ++s) {
        float gam = gammas[s];                       // uniform -> s_load
#pragma unroll 4
        for (int u = 0; u < 16; ++u) {
            const int jj = __builtin_amdgcn_readfirstlane((wave << 4) + u);
            const float4* Rr = (const float4*)(R + jj * 64);   // uniform addr
            float a0 = 0.f, a1 = 0.f, a2 = 0.f, a3 = 0.f;
#pragma unroll
            for (int q = 0; q < 16; ++q) {
                float4 rv = Rr[q];                   // -> s_load_dwordx4
                a0 += f[4 * q + 0] * rv.x;
                a1 += f[4 * q + 1] * rv.y;
                a2 += f[4 * q + 2] * rv.z;
                a3 += f[4 * q + 3] * rv.w;
            }
            float mij = (a0 + a1) + (a2 + a3);       // (F R)[i][jj]
            float d = 1.f / (R[jj * 64 + jj] + gam); // scalar load + v_rcp
            float del = (lane == jj) ? 1.f : 0.f;
            sFT[jj * 65 + lane] += d * (del - mij);  // F_{s+1}[i][jj]
        }
        __syncthreads();
#pragma unroll
        for (int m = 0; m < 64; ++m) f[m] = sFT[m * 65 + lane];  // refill row
        __syncthreads();
    }

    // GT[n][lane] = sum_m F[lane][m] * PhiT[n][m], PhiT rows via scalar path
    for (int n = wave; n < NDIM; n += 4) {
        const int nn = __builtin_amdgcn_readfirstlane(n);
        const float4* pr = (const float4*)(PhiT + nn * 64);     // uniform addr
        float a0 = 0.f, a1 = 0.f, a2 = 0.f, a3 = 0.f;
#pragma unroll
        for (int q = 0; q < 16; ++q) {
            float4 pv = pr[q];                       // -> s_load_dwordx4
            a0 += f[4 * q + 0] * pv.x;
            a1 += f[4 * q + 1] * pv.y;
            a2 += f[4 * q + 2] * pv.z;
            a3 += f[4 * q + 3] * pv.w;
        }
        GT[nn * 64 + lane] = (a0 + a1) + (a2 + a3);
    }
}

// ---------------------------------------------------------------- kernel C
// Column-owner GEMM: thread owns output column `col`, keeps G[:,col] in 64
// VGPRs. __launch_bounds__(128, 4): target 4 waves/EU -> VGPR cap 128, so
// the backend does NOT rematerialize g[] into the loop (round-5 failure
// mode: default 8-waves/EU target -> 40 VGPR -> g re-loaded per row).
// y-row address uniform in blockIdx+loop-counter -> s_load broadcast.
// Stores contiguous 484B per row, no LDS.
__global__ __launch_bounds__(128, 4) void gemm_kernel(const float* __restrict__ y,
                                                      const float* __restrict__ GT,
                                                      float* __restrict__ out) {
    const int tid = threadIdx.x;                 // 0..127
    const int col = (tid < NDIM) ? tid : (NDIM - 1);

    float g[64];
    {
        const float4* gp = (const float4*)(GT + col * 64);
#pragma unroll
        for (int q = 0; q < 16; ++q) {
            float4 t = gp[q];
            g[4 * q + 0] = t.x; g[4 * q + 1] = t.y;
            g[4 * q + 2] = t.z; g[4 * q + 3] = t.w;
        }
    }

    const long long r0 = (long long)blockIdx.x * RPB;
#pragma unroll 4
    for (int i = 0; i < RPB; ++i) {
        const long long r = r0 + i;
        const float4* yr = (const float4*)(y + r * 64);   // wave-uniform
        float a0 = 0.f, a1 = 0.f, a2 = 0.f, a3 = 0.f;
#pragma unroll
        for (int q = 0; q < 16; ++q) {
            float4 t = yr[q];                             // -> s_load_dwordx4
            a0 += g[4 * q + 0] * t.x;
            a1 += g[4 * q + 1] * t.y;
            a2 += g[4 * q + 2] * t.z;
            a3 += g[4 * q + 3] * t.w;
        }
        if (tid < NDIM)
            out[r * NDIM + tid] = (a0 + a1) + (a2 + a3);
    }
}

extern "C" void kernel_launch(void* const* d_in, const int* in_sizes, int n_in,
                              void* d_out, int out_size, void* d_ws, size_t ws_size,
                              hipStream_t stream) {
    const float* y      = (const float*)d_in[0];
    const float* Phi    = (const float*)d_in[1];
    const float* gammas = (const float*)d_in[2];
    float* out = (float*)d_out;

    float* R    = (float*)d_ws;
    float* PhiT = R + 4096;
    float* GT   = R + 12288;

    prep_kernel<<<(MDIM * MDIM + NDIM * MDIM + 255) / 256, 256, 0, stream>>>(Phi, R, PhiT);
    fmat_kernel<<<1, 256, 0, stream>>>(R, PhiT, gammas, GT);
    gemm_kernel<<<BROWS / RPB, 128, 0, stream>>>(y, GT, out);
}